// Round 4
// baseline (409.161 us; speedup 1.0000x reference)
//
#include <hip/hip_runtime.h>

// Problem constants: B=64, T=4096, F=64, H=256, LAM=0.5, LAG=1, ALPHA=0.5, EPS=1e-8
constexpr int B = 64;
constexpr int T = 4096;
constexpr int F = 64;       // == wavefront size; lane <-> feature
constexpr int H = 256;
constexpr float EPSC = 1e-8f;
constexpr float ALPHAC = 0.5f;

constexpr int C = 64;               // scan chunk length (one wave-task per chunk)
constexpr int W = 24;               // warmup steps (lambda=0.5 -> 2^-24 rel state error, thr 3.9e-2)
constexpr int CHUNKS = T / C;       // 64 chunks per batch row
constexpr int NTASK = B * CHUNKS;   // 4096 wave-tasks -> 16 waves/CU (4/SIMD)
constexpr int K_BLOCKS = NTASK / 4; // 1024 blocks x 4 waves

// ws layout (floats): [0, NTASK) penalty partials, [NTASK, NTASK+K_BLOCKS) mse partials
#define WS_PEN 0
#define WS_MSE NTASK

// ---------------------------------------------------------------------------
// Fused kernel: per wave-task (b, chunk) run the EWA scan over C t-steps.
// Per step: load the 1 KB fg row (float4/lane), butterfly-reduce to fgsum_t,
// load 256 B of seq, scan update, acc += (1-|ac_f|)*fgsum_t per lane.
// fg read exactly once globally (chunks partition t). Depth-4 register
// prefetch. 4 waves/SIMD interleave the per-step dependent chains.
// ---------------------------------------------------------------------------
__global__ __launch_bounds__(256) void k_fused(
    const float* __restrict__ seq,
    const float* __restrict__ fg,
    const float* __restrict__ inp,
    const float* __restrict__ tgt,
    float* __restrict__ ws) {
  const int lane = threadIdx.x & 63;
  const int task = blockIdx.x * (blockDim.x >> 6) + (threadIdx.x >> 6);
  const int b = task / CHUNKS;
  const int ci = task % CHUNKS;
  const int t0 = ci * C;
  const int tend = t0 + C;

  const float* sp = seq + (size_t)b * T * F + lane;        // + t*F
  const float* gp = fg + (size_t)b * T * H + lane * 4;     // + t*H (float4)

  float m = 0.f, v = 0.f, c = 0.f, acc = 0.f;
  float xl = 0.f;

  if (ci == 0) {
    v = EPSC;  // exact initial state; t=0 handled in-loop (ac=0 contribution)
  } else {
    // warmup: W seq-only steps, pipelined depth 4 (fully unrolled)
    const int ts = t0 - W;
    xl = sp[(ts - 1) * F];
    float xw[4];
#pragma unroll
    for (int j = 0; j < 4; ++j) xw[j] = sp[(ts + j) * F];
#pragma unroll
    for (int i = 0; i < W; ++i) {
      const float xt = xw[i & 3];
      if (i + 4 < W) xw[i & 3] = sp[(ts + i + 4) * F];
      m = 0.5f * (m + xt);
      const float d = xt - m;
      v = 0.5f * fmaf(d, d, v);
      c = 0.5f * fmaf(d, xl - m, c);
      xl = xt;
    }
  }

  // main loop: exactly C steps (chunk 0's t=0 pad step is a wave-uniform branch)
  float4 qb[4];
  float xb[4];
#pragma unroll
  for (int j = 0; j < 4; ++j) {
    qb[j] = *reinterpret_cast<const float4*>(gp + (size_t)(t0 + j) * H);
    xb[j] = sp[(t0 + j) * F];
  }

#pragma unroll 4
  for (int i = 0; i < C; ++i) {
    const int tt = t0 + i;
    const float4 q = qb[i & 3];
    const float xt = xb[i & 3];
    int tp = tt + 4;
    tp = (tp < tend) ? tp : (tend - 1);   // clamped tail re-load (L1-hot)
    qb[i & 3] = *reinterpret_cast<const float4*>(gp + (size_t)tp * H);
    xb[i & 3] = sp[tp * F];

    // fg row-sum -> broadcast to all lanes
    float s = (q.x + q.y) + (q.z + q.w);
#pragma unroll
    for (int off = 32; off; off >>= 1) s += __shfl_xor(s, off, 64);

    if (tt != 0) {          // wave-uniform (only chunk 0 sees tt==0)
      m = 0.5f * (m + xt);
      const float d = xt - m;
      v = 0.5f * fmaf(d, d, v);
      c = 0.5f * fmaf(d, xl - m, c);
      const float ac = c * rsqrtf(fmaf(v, v, EPSC));
      acc = fmaf(1.0f - fabsf(ac), s, acc);
    } else {
      acc += s;             // t=0: ac=0 -> irrelevance=1; state stays initial
    }
    xl = xt;
  }

#pragma unroll
  for (int off = 32; off; off >>= 1) acc += __shfl_xor(acc, off, 64);
  if (lane == 0) ws[WS_PEN + task] = acc;

  // ---- MSE partial (input/target are (B,T,1) -> B*T floats each) ----
  float macc = 0.f;
  const int gid = blockIdx.x * blockDim.x + threadIdx.x;
  const int nt = gridDim.x * blockDim.x;
  const int R = B * T;
  for (int i = gid; i < R; i += nt) {
    const float d = inp[i] - tgt[i];
    macc = fmaf(d, d, macc);
  }
#pragma unroll
  for (int off = 32; off; off >>= 1) macc += __shfl_xor(macc, off, 64);
  __shared__ float sm[4];
  if ((threadIdx.x & 63) == 0) sm[threadIdx.x >> 6] = macc;
  __syncthreads();
  if (threadIdx.x == 0)
    ws[WS_MSE + blockIdx.x] = (sm[0] + sm[1]) + (sm[2] + sm[3]);
}

// ---------------------------------------------------------------------------
// Final reduce: NTASK penalty partials + K_BLOCKS mse partials (20 KB, L2-hot).
// ---------------------------------------------------------------------------
__global__ __launch_bounds__(256) void k_reduce(
    const float* __restrict__ ws,
    float* __restrict__ out) {
  float p = 0.f, mt = 0.f;
#pragma unroll
  for (int i = 0; i < NTASK / 256; ++i)
    p += ws[WS_PEN + threadIdx.x + i * 256];
#pragma unroll
  for (int i = 0; i < K_BLOCKS / 256; ++i)
    mt += ws[WS_MSE + threadIdx.x + i * 256];
#pragma unroll
  for (int off = 32; off; off >>= 1) {
    p += __shfl_xor(p, off, 64);
    mt += __shfl_xor(mt, off, 64);
  }
  __shared__ float sm[8];
  if ((threadIdx.x & 63) == 0) {
    sm[(threadIdx.x >> 6) * 2] = p;
    sm[(threadIdx.x >> 6) * 2 + 1] = mt;
  }
  __syncthreads();
  if (threadIdx.x == 0) {
    const float pt = sm[0] + sm[2] + sm[4] + sm[6];
    const float ms = sm[1] + sm[3] + sm[5] + sm[7];
    const float R = (float)B * (float)T;
    const float pscale = ALPHAC / (R * (float)H * (float)F);
    out[0] = ms / R + pt * pscale;
  }
}

extern "C" void kernel_launch(void* const* d_in, const int* in_sizes, int n_in,
                              void* d_out, int out_size, void* d_ws, size_t ws_size,
                              hipStream_t stream) {
  const float* inp = (const float*)d_in[0];   // (B,T,1)
  const float* tgt = (const float*)d_in[1];   // (B,T,1)
  const float* seq = (const float*)d_in[2];   // (B,T,F)
  const float* fg  = (const float*)d_in[3];   // (B,T,H)
  float* out = (float*)d_out;                 // scalar
  float* ws  = (float*)d_ws;

  k_fused<<<K_BLOCKS, 256, 0, stream>>>(seq, fg, inp, tgt, ws);
  k_reduce<<<1, 256, 0, stream>>>(ws, out);
}